// Round 8
// baseline (183.698 us; speedup 1.0000x reference)
//
#include <hip/hip_runtime.h>
#include <hip/hip_bf16.h>
#include <stdint.h>

// Problem constants
#define BB   32
#define CIN  128
#define HH   64
#define WW   64
#define COUT 256
#define OHH  62
#define OWW  62
#define PIX_PER_B (OHH*OWW)        // 3844
#define NPIX (BB*PIX_PER_B)        // 123008 = 961 * 128
#define KTOT (9*CIN)               // 1152
#define NKT  36                    // K-tiles of BK=32
#define SLOT 8192                  // X-only slot: 128 pix x 32 k x 2B

typedef __bf16 bf16x8 __attribute__((ext_vector_type(8)));
typedef float  f32x4  __attribute__((ext_vector_type(4)));
typedef uint16_t u16x8 __attribute__((ext_vector_type(8)));

__device__ __forceinline__ uint16_t f2bf(float f) {
    uint32_t u = __float_as_uint(f);
    uint32_t r = (u + 0x7FFFu + ((u >> 16) & 1u)) >> 16;
    return (uint16_t)r;
}

__device__ __forceinline__ void gload_lds16(const void* g, void* l) {
    __builtin_amdgcn_global_load_lds(
        (const __attribute__((address_space(1))) uint32_t*)g,
        (__attribute__((address_space(3))) uint32_t*)l, 16, 0, 0);
}

// -------- Prepass 1: NCHW fp32 -> NHWC bf16 ----------------------------------
__global__ void __launch_bounds__(256) to_nhwc(const float* __restrict__ in,
                                               uint16_t* __restrict__ out) {
    int slab = blockIdx.x;            // b*64 + h
    int b = slab >> 6, h = slab & 63;
    int w  = threadIdx.x & 63;
    int cp = threadIdx.x >> 6;        // 0..3
    const float* src = in + (((size_t)b * CIN) * HH + h) * WW + w;
    uint16_t* dst = out + ((size_t)slab * WW + w) * CIN;
    #pragma unroll
    for (int it = 0; it < 4; ++it) {
        int c0 = cp * 32 + it * 8;
        u16x8 v;
        #pragma unroll
        for (int j = 0; j < 8; ++j) v[j] = f2bf(src[(c0 + j) * (HH * WW)]);
        *reinterpret_cast<u16x8*>(dst + c0) = v;
    }
}

// -------- Prepass 2: OIHW fp32 -> bf16 [o][uv*128 + c] -----------------------
__global__ void __launch_bounds__(256) pack_w(const float* __restrict__ w,
                                              uint16_t* __restrict__ out) {
    int idx = blockIdx.x * 256 + threadIdx.x;     // < 256*1152
    int o = idx / KTOT;
    int k = idx - o * KTOT;
    int uv = k >> 7, c = k & 127;
    out[idx] = f2bf(w[(o * CIN + c) * 9 + uv]);
}

// -------- Main: 256x128 tile, 4 waves (2Mx2N, 128x64 each), BK=32 ------------
// A (weights, 576KB, L2-resident) is NOT staged in LDS: each wave loads its 8
// A-frags per phase directly global->VGPR (dwordx4, 16B/lane contiguous along
// k; lanes l,l+16,l+32,l+48 share one 64B sector), DOUBLE-BUFFERED in regs
// (afA/afB) so each frag has a full phase of latency cover. LDS stages only X
// (8KB/slot, ring-3). Per block-phase LDS traffic: 8KB write + 16KB read
// (was 72KB) -> MFMA becomes the binding resource. Counted vmcnt(10): after
// issuing stage(t+2)[2] + A(t+1)[8], retire down to 10 -> stage(t+1)+A(t)
// complete, newest 10 in flight. One barrier per phase (ring-3 WAR-safe).
__global__ void __launch_bounds__(256, 2) conv_areg(
        const uint16_t* __restrict__ Xg,   // NHWC bf16 [32][64][64][128]
        const uint16_t* __restrict__ Wg,   // bf16 [256][1152], k=(uv,c)
        const float*    __restrict__ bias, // [256]
        float*          __restrict__ out)  // NCHW fp32 [32][256][62][62]
{
    __shared__ char lds[3 * SLOT + 1024];
    int* pbase = (int*)(lds + 3 * SLOT);   // [128] NHWC elem off of pixel
    int* obase = pbase + 128;              // [128] out flat base (o=0)

    const int tid  = threadIdx.x;
    const int lane = tid & 63;
    const int wid  = tid >> 6;             // 0..3

    // bijective XCD swizzle: nwg=961, q=120, r=1
    int bid = blockIdx.x;
    int xcd = bid & 7, lid = bid >> 3;
    int nt  = (xcd == 0 ? lid : 121 + (xcd - 1) * 120 + lid);

    if (tid < 128) {
        int n   = nt * 128 + tid;
        int b   = n / PIX_PER_B;
        int rem = n - b * PIX_PER_B;
        int oh  = rem / OWW;
        int ow  = rem - oh * OWW;
        pbase[tid] = ((b * 64 + oh) * 64 + ow) * 128;
        obase[tid] = b * (COUT * PIX_PER_B) + rem;
    }
    __syncthreads();

    // ---- X staging geometry: 2 gll/thread; row = tid>>2 (+64), chunk tid&3,
    // stored chunk holds logical chunk (tid&3)^((row>>1)&3) = (tid&3)^((tid>>3)&3)
    const int cs   = (((tid & 3) ^ ((tid >> 3) & 3)) << 4);
    const int ldst = tid * 16;
    const char* XgB = (const char*)Xg;
    const char* xptr0 = XgB + pbase[(tid >> 2)] * 2 + cs;
    const char* xptr1 = XgB + pbase[(tid >> 2) + 64] * 2 + cs;

    auto stageX = [&](int t, char* dst) {
        int uvv = t >> 2;
        int u   = (uvv * 11) >> 5;             // uvv/3 for uvv<9
        int v   = uvv - u * 3;
        int xo  = (u << 14) | (v << 8) | ((t & 3) << 6);
        gload_lds16(xptr0 + xo, dst + ldst);
        gload_lds16(xptr1 + xo, dst + 4096 + ldst);
    };

    // ---- A fragment global source: per-lane byte base within Wg ----
    const int wm = wid >> 1, wn = wid & 1;     // 2 M-waves x 2 N-waves
    const char* ap = (const char*)Wg +
                     (wm * 128 + (lane & 15)) * (KTOT * 2) + ((lane >> 4) << 4);

    // ---- xf frag ds_read byte offsets (slot-relative) ----
    int xro[4];
    #pragma unroll
    for (int nj = 0; nj < 4; ++nj) {
        int row = wn * 64 + nj * 16 + (lane & 15);
        xro[nj] = row * 64 + ((((lane >> 4) ^ ((row >> 1) & 3))) << 4);
    }

    f32x4 acc[8][4] = {};
    bf16x8 afA[8], afB[8];

#define LOADA(T, AF) do {                                                      \
    const char* _a = ap + (T) * 64;                                            \
    _Pragma("unroll") for (int mi = 0; mi < 8; ++mi)                           \
        AF[mi] = *reinterpret_cast<const bf16x8*>(_a + mi * 36864);            \
} while (0)

// Phase T: stage X(T+2) -> slot S2; load A(T+1) -> AFN; ds_read xf(T) from
// slot S; vmcnt(VMC); 32 MFMA on AFC; barrier.
#define PH(T, S, S2, AFC, AFN, STG, ALD, VMC, BAR) do {                        \
    if (STG) stageX((T) + 2, lds + (S2) * SLOT);                               \
    if (ALD) LOADA((T) + 1, AFN);                                              \
    bf16x8 xf[4];                                                              \
    _Pragma("unroll") for (int nj = 0; nj < 4; ++nj)                           \
        xf[nj] = *reinterpret_cast<const bf16x8*>(lds + (S) * SLOT + xro[nj]); \
    asm volatile("s_waitcnt vmcnt(" #VMC ")" ::: "memory");                    \
    __builtin_amdgcn_s_setprio(1);                                             \
    _Pragma("unroll") for (int mi = 0; mi < 8; ++mi)                           \
      _Pragma("unroll") for (int nj = 0; nj < 4; ++nj)                         \
        acc[mi][nj] = __builtin_amdgcn_mfma_f32_16x16x32_bf16(                 \
            AFC[mi], xf[nj], acc[mi][nj], 0, 0, 0);                            \
    __builtin_amdgcn_s_setprio(0);                                             \
    if (BAR) __builtin_amdgcn_s_barrier();                                     \
} while (0)

    // ---- prologue: X(0); A(0)->afA; X(1); wait X(0)+A(0) (X(1) in flight) ----
    stageX(0, lds);
    LOADA(0, afA);
    stageX(1, lds + SLOT);
    asm volatile("s_waitcnt vmcnt(2)" ::: "memory");
    __builtin_amdgcn_s_barrier();

    // ---- main: 5 x 6 phases (t=0..29), peeled tail t=30..35 ----
    for (int i = 0; i < 5; ++i) {
        const int t = 6 * i;
        PH(t + 0, 0, 2, afA, afB, 1, 1, 10, 1);
        PH(t + 1, 1, 0, afB, afA, 1, 1, 10, 1);
        PH(t + 2, 2, 1, afA, afB, 1, 1, 10, 1);
        PH(t + 3, 0, 2, afB, afA, 1, 1, 10, 1);
        PH(t + 4, 1, 0, afA, afB, 1, 1, 10, 1);
        PH(t + 5, 2, 1, afB, afA, 1, 1, 10, 1);
    }
    PH(30, 0, 2, afA, afB, 1, 1, 10, 1);
    PH(31, 1, 0, afB, afA, 1, 1, 10, 1);
    PH(32, 2, 1, afA, afB, 1, 1, 10, 1);
    PH(33, 0, 2, afB, afA, 1, 1, 10, 1);   // stage X(35)->slot2; A(34)->afA
    PH(34, 1, 0, afA, afB, 0, 1,  8, 1);   // no stage; A(35)->afB
    PH(35, 2, 1, afB, afA, 0, 0,  0, 0);
#undef PH
#undef LOADA

    // ---- epilogue: C/D col=lane&15 (pixel), row=(lane>>4)*4+reg (o) ----
    #pragma unroll
    for (int mi = 0; mi < 8; ++mi) {
        int o = wm * 128 + mi * 16 + ((lane >> 4) << 2);
        #pragma unroll
        for (int reg = 0; reg < 4; ++reg) {
            float bv = bias[o + reg];
            #pragma unroll
            for (int nj = 0; nj < 4; ++nj) {
                int pl = wn * 64 + nj * 16 + (lane & 15);
                out[obase[pl] + (o + reg) * PIX_PER_B] = acc[mi][nj][reg] + bv;
            }
        }
    }
}

// -------- Fallback (ws too small): naive direct conv -------------------------
__global__ void __launch_bounds__(256) conv_naive(const float* __restrict__ in,
                                                  const float* __restrict__ w,
                                                  const float* __restrict__ bias,
                                                  float* __restrict__ out) {
    long idx = (long)blockIdx.x * 256 + threadIdx.x;
    int t = (int)idx;
    int ow = t % OWW; t /= OWW;
    int oh = t % OHH; t /= OHH;
    int o  = t % COUT;
    int b  = t / COUT;
    float s = bias[o];
    for (int c = 0; c < CIN; ++c)
        for (int u = 0; u < 3; ++u)
            for (int v = 0; v < 3; ++v)
                s += in[((b * CIN + c) * HH + oh + u) * WW + ow + v] *
                     w[((o * CIN + c) * 3 + u) * 3 + v];
    out[idx] = s;
}

extern "C" void kernel_launch(void* const* d_in, const int* in_sizes, int n_in,
                              void* d_out, int out_size, void* d_ws, size_t ws_size,
                              hipStream_t stream) {
    const float* in   = (const float*)d_in[0];
    const float* wt   = (const float*)d_in[1];
    const float* bias = (const float*)d_in[2];
    float* out = (float*)d_out;

    const size_t xg_elems = (size_t)BB * HH * WW * CIN;       // 33.5M bf16
    const size_t wg_elems = (size_t)COUT * KTOT;              // 295K bf16
    const size_t need = (xg_elems + wg_elems) * sizeof(uint16_t);

    if (ws_size < need) {
        long total = (long)BB * COUT * OHH * OWW;
        conv_naive<<<(int)((total + 255) / 256), 256, 0, stream>>>(in, wt, bias, out);
        return;
    }

    uint16_t* Xg = (uint16_t*)d_ws;
    uint16_t* Wg = Xg + xg_elems;

    to_nhwc<<<BB * HH, 256, 0, stream>>>(in, Xg);
    pack_w<<<(COUT * KTOT) / 256, 256, 0, stream>>>(wt, Wg);
    conv_areg<<<NPIX / 128, 256, 0, stream>>>(Xg, Wg, bias, out);
}

// Round 9
// 116.968 us; speedup vs baseline: 1.5705x; 1.5705x over previous
//
#include <hip/hip_runtime.h>
#include <hip/hip_bf16.h>
#include <stdint.h>

// Problem constants
#define BB   32
#define CIN  128
#define HH   64
#define WW   64
#define COUT 256
#define OHH  62
#define OWW  62
#define PIX_PER_B (OHH*OWW)        // 3844
#define NPIX (BB*PIX_PER_B)        // 123008 = 961 * 128
#define KTOT (9*CIN)               // 1152
#define NKT  36                    // K-tiles of BK=32
#define SLOT 24576                 // A 16KB + X 8KB per K-tile

typedef __bf16 bf16x8 __attribute__((ext_vector_type(8)));
typedef float  f32x16 __attribute__((ext_vector_type(16)));
typedef uint16_t u16x8 __attribute__((ext_vector_type(8)));

__device__ __forceinline__ uint16_t f2bf(float f) {
    uint32_t u = __float_as_uint(f);
    uint32_t r = (u + 0x7FFFu + ((u >> 16) & 1u)) >> 16;
    return (uint16_t)r;
}

__device__ __forceinline__ void gload_lds16(const void* g, void* l) {
    __builtin_amdgcn_global_load_lds(
        (const __attribute__((address_space(1))) uint32_t*)g,
        (__attribute__((address_space(3))) uint32_t*)l, 16, 0, 0);
}

// -------- Prepass 1: NCHW fp32 -> NHWC bf16 ----------------------------------
__global__ void __launch_bounds__(256) to_nhwc(const float* __restrict__ in,
                                               uint16_t* __restrict__ out) {
    int slab = blockIdx.x;            // b*64 + h
    int b = slab >> 6, h = slab & 63;
    int w  = threadIdx.x & 63;
    int cp = threadIdx.x >> 6;        // 0..3
    const float* src = in + (((size_t)b * CIN) * HH + h) * WW + w;
    uint16_t* dst = out + ((size_t)slab * WW + w) * CIN;
    #pragma unroll
    for (int it = 0; it < 4; ++it) {
        int c0 = cp * 32 + it * 8;
        u16x8 v;
        #pragma unroll
        for (int j = 0; j < 8; ++j) v[j] = f2bf(src[(c0 + j) * (HH * WW)]);
        *reinterpret_cast<u16x8*>(dst + c0) = v;
    }
}

// -------- Prepass 2: OIHW fp32 -> bf16 [o][uv*128 + c] -----------------------
__global__ void __launch_bounds__(256) pack_w(const float* __restrict__ w,
                                              uint16_t* __restrict__ out) {
    int idx = blockIdx.x * 256 + threadIdx.x;     // < 256*1152
    int o = idx / KTOT;
    int k = idx - o * KTOT;
    int uv = k >> 7, c = k & 127;
    out[idx] = f2bf(w[(o * CIN + c) * 9 + uv]);
}

// -------- Main: 256x128 tile, 8 waves (4Mx2N, 64x64 each), BK=32 -------------
// r4 skeleton with 32x32x16 MFMA: wave tile 64x64 = 2x2 of 32x32 tiles, 8
// mfma/phase (halved instr count, 2495 TF ceiling vs 2176). Frags: A row =
// lane&31, k = (lane>>5)*8+e (K-major, analog of verified 16x16x32 layout);
// C/D col=lane&31, row=(reg&3)+8*(reg>>2)+4*(lane>>5) [m74/m101]. Staging,
// swizzle, ring-3, counted vmcnt identical to r4 (isolated shape A/B).
__global__ void __launch_bounds__(512, 4) conv_k32(
        const uint16_t* __restrict__ Xg,   // NHWC bf16 [32][64][64][128]
        const uint16_t* __restrict__ Wg,   // bf16 [256][1152], k=(uv,c)
        const float*    __restrict__ bias, // [256]
        float*          __restrict__ out)  // NCHW fp32 [32][256][62][62]
{
    __shared__ char lds[3 * SLOT + 1024];
    int* pbase = (int*)(lds + 3 * SLOT);   // [128] NHWC elem off of pixel
    int* obase = pbase + 128;              // [128] out flat base (o=0)

    const int tid  = threadIdx.x;
    const int lane = tid & 63;
    const int wid  = tid >> 6;             // 0..7

    // bijective XCD swizzle: nwg=961, q=120, r=1
    int bid = blockIdx.x;
    int xcd = bid & 7, lid = bid >> 3;
    int nt  = (xcd == 0 ? lid : 121 + (xcd - 1) * 120 + lid);

    if (tid < 128) {
        int n   = nt * 128 + tid;
        int b   = n / PIX_PER_B;
        int rem = n - b * PIX_PER_B;
        int oh  = rem / OWW;
        int ow  = rem - oh * OWW;
        pbase[tid] = ((b * 64 + oh) * 64 + ow) * 128;
        obase[tid] = b * (COUT * PIX_PER_B) + rem;
    }
    __syncthreads();

    // ---- staging geometry (identical to r4) ----
    const int cs   = (((tid & 3) ^ ((tid >> 3) & 3)) << 4);
    const int ldst = tid * 16;
    const char* aptr0 = (const char*)Wg + (tid >> 2) * (KTOT * 2) + cs;
    const char* aptr1 = (const char*)Wg + (128 + (tid >> 2)) * (KTOT * 2) + cs;
    const char* xptr  = (const char*)Xg + pbase[tid >> 2] * 2 + cs;

    // ---- fragment ds_read byte offsets: 32x32x16 layout ----
    // row = tilebase + (lane&31); logical chunk = ks*2 + (lane>>5); stored
    // chunk = logical ^ ((row>>1)&3)  (same involution as staging).
    const int wm = wid >> 1, wn = wid & 1;   // 4 M-waves x 2 N-waves
    int aro[2][2], xro[2][2];
    #pragma unroll
    for (int tm = 0; tm < 2; ++tm) {
        int row = wm * 64 + tm * 32 + (lane & 31);
        #pragma unroll
        for (int ks = 0; ks < 2; ++ks)
            aro[tm][ks] = row * 64 +
                (((ks * 2 + (lane >> 5)) ^ ((row >> 1) & 3)) << 4);
    }
    #pragma unroll
    for (int tn = 0; tn < 2; ++tn) {
        int row = wn * 64 + tn * 32 + (lane & 31);
        #pragma unroll
        for (int ks = 0; ks < 2; ++ks)
            xro[tn][ks] = 16384 + row * 64 +
                (((ks * 2 + (lane >> 5)) ^ ((row >> 1) & 3)) << 4);
    }

    f32x16 acc[2][2] = {};

    auto stage = [&](int t, char* dst) {
        int uvv = t >> 2;                      // 0..8
        int u   = (uvv * 11) >> 5;             // uvv/3
        int v   = uvv - u * 3;
        int kb  = ((t & 3) << 6) + 0;          // k-quarter byte off
        gload_lds16(aptr0 + t * 64, dst + ldst);
        gload_lds16(aptr1 + t * 64, dst + 8192 + ldst);
        gload_lds16(xptr + ((u << 14) | (v << 8) | ((t & 3) << 6)),
                    dst + 16384 + ldst);
        (void)kb;
    };

    // ---- prologue: stage K-tiles 0,1 ----
    stage(0, lds);
    stage(1, lds + SLOT);
    asm volatile("s_waitcnt vmcnt(3)" ::: "memory");   // tile 0 resident
    __builtin_amdgcn_s_barrier();

    int s = 0, s2 = 2;
    for (int t = 0; t < NKT; ++t) {
        char* slot = lds + s * SLOT;
        bf16x8 af[2][2], xf[2][2];
        #pragma unroll
        for (int tm = 0; tm < 2; ++tm)
            #pragma unroll
            for (int ks = 0; ks < 2; ++ks)
                af[tm][ks] = *reinterpret_cast<const bf16x8*>(slot + aro[tm][ks]);
        #pragma unroll
        for (int tn = 0; tn < 2; ++tn)
            #pragma unroll
            for (int ks = 0; ks < 2; ++ks)
                xf[tn][ks] = *reinterpret_cast<const bf16x8*>(slot + xro[tn][ks]);
        if (t + 2 < NKT) stage(t + 2, lds + s2 * SLOT);
        __builtin_amdgcn_s_barrier();
        asm volatile("s_waitcnt lgkmcnt(0)" ::: "memory");
        __builtin_amdgcn_sched_barrier(0);
        __builtin_amdgcn_s_setprio(1);
        #pragma unroll
        for (int tm = 0; tm < 2; ++tm)
            #pragma unroll
            for (int tn = 0; tn < 2; ++tn)
                #pragma unroll
                for (int ks = 0; ks < 2; ++ks)
                    acc[tm][tn] = __builtin_amdgcn_mfma_f32_32x32x16_bf16(
                        af[tm][ks], xf[tn][ks], acc[tm][tn], 0, 0, 0);
        __builtin_amdgcn_s_setprio(0);
        if (t < NKT - 2)
            asm volatile("s_waitcnt vmcnt(3)" ::: "memory");
        else if (t == NKT - 2)
            asm volatile("s_waitcnt vmcnt(0)" ::: "memory");
        __builtin_amdgcn_s_barrier();
        s  = (s  == 2) ? 0 : s  + 1;
        s2 = (s2 == 2) ? 0 : s2 + 1;
    }

    // ---- epilogue: 32x32 C/D: col=lane&31 (pixel), row=(reg&3)+8*(reg>>2)
    //      +4*(lane>>5) (o) ----
    #pragma unroll
    for (int tm = 0; tm < 2; ++tm) {
        #pragma unroll
        for (int tn = 0; tn < 2; ++tn) {
            int pl = wn * 64 + tn * 32 + (lane & 31);
            int ob = obase[pl];
            #pragma unroll
            for (int reg = 0; reg < 16; ++reg) {
                int o = wm * 64 + tm * 32 +
                        (reg & 3) + 8 * (reg >> 2) + 4 * (lane >> 5);
                out[ob + o * PIX_PER_B] = acc[tm][tn][reg] + bias[o];
            }
        }
    }
}

// -------- Fallback (ws too small): naive direct conv -------------------------
__global__ void __launch_bounds__(256) conv_naive(const float* __restrict__ in,
                                                  const float* __restrict__ w,
                                                  const float* __restrict__ bias,
                                                  float* __restrict__ out) {
    long idx = (long)blockIdx.x * 256 + threadIdx.x;
    int t = (int)idx;
    int ow = t % OWW; t /= OWW;
    int oh = t % OHH; t /= OHH;
    int o  = t % COUT;
    int b  = t / COUT;
    float s = bias[o];
    for (int c = 0; c < CIN; ++c)
        for (int u = 0; u < 3; ++u)
            for (int v = 0; v < 3; ++v)
                s += in[((b * CIN + c) * HH + oh + u) * WW + ow + v] *
                     w[((o * CIN + c) * 3 + u) * 3 + v];
    out[idx] = s;
}

extern "C" void kernel_launch(void* const* d_in, const int* in_sizes, int n_in,
                              void* d_out, int out_size, void* d_ws, size_t ws_size,
                              hipStream_t stream) {
    const float* in   = (const float*)d_in[0];
    const float* wt   = (const float*)d_in[1];
    const float* bias = (const float*)d_in[2];
    float* out = (float*)d_out;

    const size_t xg_elems = (size_t)BB * HH * WW * CIN;       // 33.5M bf16
    const size_t wg_elems = (size_t)COUT * KTOT;              // 295K bf16
    const size_t need = (xg_elems + wg_elems) * sizeof(uint16_t);

    if (ws_size < need) {
        long total = (long)BB * COUT * OHH * OWW;
        conv_naive<<<(int)((total + 255) / 256), 256, 0, stream>>>(in, wt, bias, out);
        return;
    }

    uint16_t* Xg = (uint16_t*)d_ws;
    uint16_t* Wg = Xg + xg_elems;

    to_nhwc<<<BB * HH, 256, 0, stream>>>(in, Xg);
    pack_w<<<(COUT * KTOT) / 256, 256, 0, stream>>>(wt, Wg);
    conv_k32<<<NPIX / 128, 512, 0, stream>>>(Xg, Wg, bias, out);
}